// Round 6
// baseline (1661.783 us; speedup 1.0000x reference)
//
#include <hip/hip_runtime.h>
#include <hip/hip_bf16.h>

static constexpr int KD  = 64;
static constexpr int KH  = 64;

typedef __attribute__((ext_vector_type(8))) short bf16x8;
typedef __attribute__((ext_vector_type(4))) float f32x4;
typedef __attribute__((ext_vector_type(2))) float f32x2;

__device__ inline unsigned short f2bf(float f) {
  union { float f; unsigned u; } uf; uf.f = f;
  unsigned u = uf.u;
  return (unsigned short)((u + 0x7FFFu + ((u >> 16) & 1u)) >> 16);
}
__device__ inline float bf2f(unsigned short h) {
  union { unsigned u; float f; } x; x.u = ((unsigned)h) << 16; return x.f;
}
__device__ inline bf16x8 pack8(const float* p) {
  float4 lo = *(const float4*)p;
  float4 hi = *(const float4*)(p + 4);
  bf16x8 v;
  v[0] = (short)f2bf(lo.x); v[1] = (short)f2bf(lo.y);
  v[2] = (short)f2bf(lo.z); v[3] = (short)f2bf(lo.w);
  v[4] = (short)f2bf(hi.x); v[5] = (short)f2bf(hi.y);
  v[6] = (short)f2bf(hi.z); v[7] = (short)f2bf(hi.w);
  return v;
}
__device__ inline float sigm(float x) { return 1.0f / (1.0f + __expf(-x)); }
__device__ inline float silu_(float x) { return x * sigm(x); }
__device__ inline void atomic_fadd(float* p, float v) {
  asm volatile("global_atomic_add_f32 %0, %1, off" :: "v"(p), "v"(v) : "memory");
}
// 4×f32 -> 4×fp8(e4m3, HW-consistent) packed in a uint
__device__ inline unsigned pk_fp8x4(float a0, float a1, float a2, float a3) {
  int v = __builtin_amdgcn_cvt_pk_fp8_f32(a0, a1, 0, false);
  v = __builtin_amdgcn_cvt_pk_fp8_f32(a2, a3, v, true);
  return (unsigned)v;
}
// sum of four fp8x4 words -> out[0..3]
__device__ inline void sum4_fp8(unsigned a, unsigned b, unsigned c, unsigned d, float* out) {
  f32x2 a0 = __builtin_amdgcn_cvt_pk_f32_fp8((int)a, false);
  f32x2 b0 = __builtin_amdgcn_cvt_pk_f32_fp8((int)b, false);
  f32x2 c0 = __builtin_amdgcn_cvt_pk_f32_fp8((int)c, false);
  f32x2 d0 = __builtin_amdgcn_cvt_pk_f32_fp8((int)d, false);
  out[0] = (a0[0] + b0[0]) + (c0[0] + d0[0]);
  out[1] = (a0[1] + b0[1]) + (c0[1] + d0[1]);
  f32x2 a1 = __builtin_amdgcn_cvt_pk_f32_fp8((int)a, true);
  f32x2 b1 = __builtin_amdgcn_cvt_pk_f32_fp8((int)b, true);
  f32x2 c1 = __builtin_amdgcn_cvt_pk_f32_fp8((int)c, true);
  f32x2 d1 = __builtin_amdgcn_cvt_pk_f32_fp8((int)d, true);
  out[2] = (a1[0] + b1[0]) + (c1[0] + d1[0]);
  out[3] = (a1[1] + b1[1]) + (c1[1] + d1[1]);
}

// ---------------- K0: frag-major W1 segment tables (bf16) + W2/Wo transposes ----
__global__ void k_prep(const float* __restrict__ wc1, const float* __restrict__ wg1,
                       const float* __restrict__ wc2, const float* __restrict__ wg2,
                       const float* __restrict__ wo,
                       const float* __restrict__ bc1, const float* __restrict__ bg1,
                       unsigned short* __restrict__ wpb, unsigned short* __restrict__ wpa,
                       unsigned short* __restrict__ wpg,
                       unsigned short* __restrict__ wc2t, unsigned short* __restrict__ wg2t,
                       unsigned short* __restrict__ wot, float* __restrict__ biaspg) {
  int t = blockIdx.x * 256 + threadIdx.x;
  if (t < 16384) {          // wpb: NOUT=256
    int blk = t >> 9, n = blk >> 1, s = blk & 1;
    int lane = (t >> 3) & 63, e = t & 7;
    int p = lane >> 4, q = lane & 15;
    int k = 32 * s + 8 * p + e;
    int o = 16 * n + q;
    float v;
    if (o < 64)       v = wc1[k * KH + o];                 // core1 (rows 0:64)
    else if (o < 128) v = wg1[k * KH + (o - 64)];          // gate1
    else if (o < 192) v = wc1[(64 + k) * KH + (o - 128)];  // core2 (rows 64:128)
    else              v = wg1[(64 + k) * KH + (o - 192)];  // gate2
    wpb[t] = f2bf(v);
  }
  if (t < 8192) {           // wpa / wpg: NOUT=128
    int blk = t >> 9, n = blk >> 1, s = blk & 1;
    int lane = (t >> 3) & 63, e = t & 7;
    int p = lane >> 4, q = lane & 15;
    int k = 32 * s + 8 * p + e;
    int o = 16 * n + q;
    float va = (o < 64) ? wc1[(192 + k) * KH + o] : wg1[(192 + k) * KH + (o - 64)];
    wpa[t] = f2bf(va);
    float vg = (o < 64) ? wc1[(128 + k) * KH + o] : wg1[(128 + k) * KH + (o - 64)];
    wpg[t] = f2bf(vg);
  }
  if (t < KH * KD) {        // natural B^T [d][k]
    int d = t >> 6, k = t & 63;
    wc2t[t] = f2bf(wc2[k * KD + d]);
    wg2t[t] = f2bf(wg2[k * KD + d]);
    wot[t]  = f2bf(wo[k * KD + d]);
  }
  if (t < 128) biaspg[t] = (t < 64) ? bc1[t] : bg1[t - 64];
}

// bond_weights (first na rows) -> bf16 table
__global__ void k_bw16(const float* __restrict__ bwt, unsigned short* __restrict__ bw16, int n8) {
  int t = blockIdx.x * 256 + threadIdx.x;
  if (t < n8) *(bf16x8*)(bw16 + (long)t * 8) = pack8(bwt + (long)t * 8);
}

// ---------------- passA: P[r][NOUT] = X[r][0:64] @ Wseg (+bias), fp8 out ------
template<int NOUT>
__global__ __launch_bounds__(256) void k_partial(
    const float* __restrict__ X, const unsigned short* __restrict__ wfrag,
    const float* __restrict__ bias, unsigned char* __restrict__ P, int nrows) {
  constexpr int NSH = NOUT * 64;
  __shared__ unsigned short wl[NSH];
  const int tid = threadIdx.x;
  for (int c = tid * 8; c < NSH; c += 256 * 8)
    *(bf16x8*)&wl[c] = *(const bf16x8*)&wfrag[c];
  __syncthreads();
  const int wave = tid >> 6, lane = tid & 63, p = lane >> 4, q = lane & 15;
  const int ntile = (nrows + 63) >> 6;
  for (int tile = blockIdx.x; tile < ntile; tile += gridDim.x) {
    const int r0 = tile * 64 + wave * 16 + q;
    const int r = (r0 < nrows) ? r0 : (nrows - 1);
    bf16x8 b[2];
    b[0] = pack8(X + (long)r * 64 + 8 * p);
    b[1] = pack8(X + (long)r * 64 + 32 + 8 * p);
    unsigned char* dst = P + (long)r0 * NOUT;
#pragma unroll
    for (int n = 0; n < NOUT / 16; n++) {
      f32x4 acc;
      if (bias) acc = (f32x4&)*(const float4*)(bias + 16 * n + 4 * p);
      else      acc = (f32x4){0.f, 0.f, 0.f, 0.f};
#pragma unroll
      for (int s = 0; s < 2; s++) {
        bf16x8 a = *(const bf16x8*)&wl[((n * 2 + s) * 64 + lane) * 8];
        acc = __builtin_amdgcn_mfma_f32_16x16x32_bf16(a, b[s], acc, 0, 0, 0);
      }
      if (r0 < nrows)
        *(unsigned*)(dst + 16 * n + 4 * p) = pk_fp8x4(acc[0], acc[1], acc[2], acc[3]);
    }
  }
}

// ---------------- CSR build (binned by bi, bins = na) ----------------
__global__ void k_hist(const int* __restrict__ bgr, int* __restrict__ cnt, int ng) {
  int g = blockIdx.x * blockDim.x + threadIdx.x;
  if (g < ng) atomicAdd(&cnt[bgr[3 * g + 1]], 1);
}

__global__ __launch_bounds__(256) void k_scan1(const int* __restrict__ cnt,
                                               int* __restrict__ part,
                                               int* __restrict__ bsum, int n) {
  __shared__ int wsum[4];
  const int tid = threadIdx.x;
  const int i = blockIdx.x * 256 + tid;
  const int lane = tid & 63, w = tid >> 6;
  int orig = (i < n) ? cnt[i] : 0;
  int v = orig;
#pragma unroll
  for (int d = 1; d < 64; d <<= 1) {
    int t = __shfl_up(v, d);
    if (lane >= d) v += t;
  }
  if (lane == 63) wsum[w] = v;
  __syncthreads();
  int add = 0;
  for (int k = 0; k < w; k++) add += wsum[k];
  v += add;
  if (i < n) part[i] = v - orig;
  if (tid == 255) bsum[blockIdx.x] = v;
}

__global__ __launch_bounds__(1024) void k_scan2(const int* __restrict__ bsum,
                                                int* __restrict__ bscan, int nblk) {
  __shared__ int wsum[16];
  const int tid = threadIdx.x;
  const int lane = tid & 63, w = tid >> 6;
  int orig = (tid < nblk) ? bsum[tid] : 0;
  int v = orig;
#pragma unroll
  for (int d = 1; d < 64; d <<= 1) {
    int t = __shfl_up(v, d);
    if (lane >= d) v += t;
  }
  if (lane == 63) wsum[w] = v;
  __syncthreads();
  int add = 0;
  for (int k = 0; k < w; k++) add += wsum[k];
  v += add;
  if (tid < nblk) bscan[tid] = v - orig;
}

__global__ void k_scan3(const int* __restrict__ part, const int* __restrict__ bscan,
                        int* __restrict__ off, int* __restrict__ cur, int n) {
  int i = blockIdx.x * blockDim.x + threadIdx.x;
  if (i < n) {
    off[i] = part[i] + bscan[i >> 8];
    cur[i] = 0;
  }
}

// fill packed records sorted by bi: {g, ci, bj, bi}
__global__ void k_fill(const int* __restrict__ bgr, const int* __restrict__ off,
                       int* __restrict__ cur, int4* __restrict__ ids4, int ng) {
  int g = blockIdx.x * blockDim.x + threadIdx.x;
  if (g < ng) {
    int ci = bgr[3 * g + 0];
    int bi = bgr[3 * g + 1];
    int bj = bgr[3 * g + 2];
    int slot = atomicAdd(&cur[bi], 1);
    int4 r; r.x = g; r.y = ci; r.z = bj; r.w = bi;
    ids4[off[bi] + slot] = r;
  }
}

// ---------------- k_agg: fp8 gather -> sum -> silu -> MFMA GEMM2 -> sorted atomics
__global__ __launch_bounds__(256) void k_agg(
    const int4* __restrict__ ids4,
    const unsigned char* __restrict__ PB, const unsigned char* __restrict__ PA,
    const unsigned char* __restrict__ PG,
    const unsigned short* __restrict__ wc2t, const unsigned short* __restrict__ wg2t,
    const float* __restrict__ bc2, const float* __restrict__ bg2,
    const unsigned short* __restrict__ bw16,
    float* __restrict__ agg, int ntot) {
  const int tid = threadIdx.x, wave = tid >> 6, lane = tid & 63;
  const int p = lane >> 4, q = lane & 15;
  const int pos = blockIdx.x * 64 + wave * 16 + q;
  const int4 r = ids4[(pos < ntot) ? pos : (ntot - 1)];
  const int g = r.x, ci = r.y, bj = r.z, bi = r.w;

  const unsigned char* rb1 = PB + (long)bi * 256;        // [c1 64|g1 64|c2 64|g2 64]
  const unsigned char* rb2 = PB + (long)bj * 256 + 128;
  const unsigned char* ra  = PA + (long)ci * 128;        // [c 64|g 64]
  const unsigned char* rg  = PG + (long)g  * 128;

  bf16x8 b2c[2], b2g[2];
#pragma unroll
  for (int s = 0; s < 2; s++) {
    const int o8 = 32 * s + 8 * p;
    uint2 v1 = *(const uint2*)(rb1 + o8);
    uint2 v2 = *(const uint2*)(rb2 + o8);
    uint2 v3 = *(const uint2*)(ra + o8);
    uint2 v4 = *(const uint2*)(rg + o8);
    uint2 w1 = *(const uint2*)(rb1 + 64 + o8);
    uint2 w2 = *(const uint2*)(rb2 + 64 + o8);
    uint2 w3 = *(const uint2*)(ra + 64 + o8);
    uint2 w4 = *(const uint2*)(rg + 64 + o8);
    float pc[8], pg_[8];
    sum4_fp8(v1.x, v2.x, v3.x, v4.x, pc + 0);
    sum4_fp8(v1.y, v2.y, v3.y, v4.y, pc + 4);
    sum4_fp8(w1.x, w2.x, w3.x, w4.x, pg_ + 0);
    sum4_fp8(w1.y, w2.y, w3.y, w4.y, pg_ + 4);
#pragma unroll
    for (int e = 0; e < 8; e++) {
      b2c[s][e] = (short)f2bf(silu_(pc[e]));
      b2g[s][e] = (short)f2bf(silu_(pg_[e]));
    }
  }

  // GEMM2 (R5-verified transposed pattern): oc[n2][j] = O[d=16n2+4p+j][angle q]
  f32x4 oc[4], og[4];
#pragma unroll
  for (int n2 = 0; n2 < 4; n2++) {
    oc[n2] = (f32x4&)*(const float4*)(bc2 + 16 * n2 + 4 * p);
    og[n2] = (f32x4&)*(const float4*)(bg2 + 16 * n2 + 4 * p);
  }
#pragma unroll
  for (int s = 0; s < 2; s++) {
    const int ko = 32 * s + 8 * p;
#pragma unroll
    for (int n2 = 0; n2 < 4; n2++) {
      bf16x8 a1 = *(const bf16x8*)(wc2t + (q + 16 * n2) * KH + ko);
      oc[n2] = __builtin_amdgcn_mfma_f32_16x16x32_bf16(a1, b2c[s], oc[n2], 0, 0, 0);
      bf16x8 a2 = *(const bf16x8*)(wg2t + (q + 16 * n2) * KH + ko);
      og[n2] = __builtin_amdgcn_mfma_f32_16x16x32_bf16(a2, b2g[s], og[n2], 0, 0, 0);
    }
  }

  // epilogue: agg[bi][d] += silu(oc)*sigm(og)*bw[bi][d]*bw[bj][d]; bi sorted ->
  // lanes in each atomic instruction hit ~2-3 distinct rows.
  if (pos < ntot) {
    float* dst = agg + (long)bi * KD;
    const unsigned short* wi = bw16 + (long)bi * KD;
    const unsigned short* wj = bw16 + (long)bj * KD;
#pragma unroll
    for (int n2 = 0; n2 < 4; n2++) {
      const int d = 16 * n2 + 4 * p;
      ushort4 a = *(const ushort4*)(wi + d);
      ushort4 b = *(const ushort4*)(wj + d);
      atomic_fadd(dst + d + 0, silu_(oc[n2][0]) * sigm(og[n2][0]) * bf2f(a.x) * bf2f(b.x));
      atomic_fadd(dst + d + 1, silu_(oc[n2][1]) * sigm(og[n2][1]) * bf2f(a.y) * bf2f(b.y));
      atomic_fadd(dst + d + 2, silu_(oc[n2][2]) * sigm(og[n2][2]) * bf2f(a.z) * bf2f(b.z));
      atomic_fadd(dst + d + 3, silu_(oc[n2][3]) * sigm(og[n2][3]) * bf2f(a.w) * bf2f(b.w));
    }
  }
}

// ---------------- K2: out = agg @ Wo + bo + bond (in place on d_out) ----------
__global__ __launch_bounds__(256) void k_out(
    const float* __restrict__ bond, const unsigned short* __restrict__ wot,
    const float* __restrict__ bo, float* __restrict__ out, int nb) {
  const int wave = threadIdx.x >> 6;
  const int lane = threadIdx.x & 63;
  const int r15 = lane & 15;
  const int ck = lane >> 4;
  const long rbase = (long)blockIdx.x * 64 + wave * 16;

  const long row = rbase + r15;
  const long rowc = (row < nb) ? row : 0;
  bf16x8 a[2];
  a[0] = pack8(out + rowc * KD + ck * 8);
  a[1] = pack8(out + rowc * KD + 32 + ck * 8);

  f32x4 acc[4];
#pragma unroll
  for (int n = 0; n < 4; n++) {
    float b = bo[n * 16 + r15];
    acc[n] = (f32x4){b, b, b, b};
  }
#pragma unroll
  for (int s = 0; s < 2; s++) {
    const int koff = s * 32 + ck * 8;
#pragma unroll
    for (int n = 0; n < 4; n++) {
      bf16x8 bf = *(const bf16x8*)(wot + (n * 16 + r15) * KH + koff);
      acc[n] = __builtin_amdgcn_mfma_f32_16x16x32_bf16(a[s], bf, acc[n], 0, 0, 0);
    }
  }
#pragma unroll
  for (int n = 0; n < 4; n++) {
#pragma unroll
    for (int j = 0; j < 4; j++) {
      const long orow = rbase + ck * 4 + j;
      if (orow < nb) {
        const int d = n * 16 + r15;
        out[orow * KD + d] = acc[n][j] + bond[orow * KD + d];
      }
    }
  }
}

extern "C" void kernel_launch(void* const* d_in, const int* in_sizes, int n_in,
                              void* d_out, int out_size, void* d_ws, size_t ws_size,
                              hipStream_t stream) {
  const float* atom = (const float*)d_in[0];
  const float* bond = (const float*)d_in[1];
  const float* bwt  = (const float*)d_in[2];
  const float* ang  = (const float*)d_in[3];
  const int*   bgr  = (const int*)d_in[4];
  const float* wc1 = (const float*)d_in[5];
  const float* bc1 = (const float*)d_in[6];
  const float* wc2 = (const float*)d_in[7];
  const float* bc2 = (const float*)d_in[8];
  const float* wg1 = (const float*)d_in[9];
  const float* bg1 = (const float*)d_in[10];
  const float* wg2 = (const float*)d_in[11];
  const float* bg2 = (const float*)d_in[12];
  const float* wo  = (const float*)d_in[13];
  const float* bo  = (const float*)d_in[14];

  const int na = in_sizes[0] / KD;   // atoms (40000); all bond_graph indices < na
  const int nb = in_sizes[1] / KD;   // bonds (200000)
  const int ng = in_sizes[4] / 3;    // angles (500000)
  float* out = (float*)d_out;

  char* pp = (char*)d_ws;
  auto alloc = [&](size_t bytes) { char* r = pp; pp += (bytes + 255) & ~(size_t)255; return r; };
  unsigned short* wpb  = (unsigned short*)alloc(16384 * 2);
  unsigned short* wpa  = (unsigned short*)alloc(8192 * 2);
  unsigned short* wpg  = (unsigned short*)alloc(8192 * 2);
  unsigned short* wc2t = (unsigned short*)alloc((size_t)KH * KD * 2);
  unsigned short* wg2t = (unsigned short*)alloc((size_t)KH * KD * 2);
  unsigned short* wot  = (unsigned short*)alloc((size_t)KH * KD * 2);
  float* biaspg        = (float*)alloc(128 * 4);
  unsigned short* bw16 = (unsigned short*)alloc((size_t)na * KD * 2);   // 5.1 MB
  unsigned char* PB    = (unsigned char*)alloc((size_t)na * 256);       // 10.2 MB
  unsigned char* PA    = (unsigned char*)alloc((size_t)na * 128);       // 5.1 MB
  unsigned char* PG    = (unsigned char*)alloc((size_t)ng * 128);       // 64 MB
  int* cnt  = (int*)alloc((size_t)na * 4);
  int* cur  = (int*)alloc((size_t)na * 4);
  int* offb = (int*)alloc((size_t)na * 4);
  int* part = (int*)alloc((size_t)na * 4);
  int4* ids4 = (int4*)alloc((size_t)ng * 16);                           // 8 MB
  int* bsum  = (int*)alloc(4096);
  int* bscan = (int*)alloc(4096);

  const int nblk = (na + 255) / 256;   // 157 <= 1024

  hipMemsetAsync(d_out, 0, (size_t)out_size * sizeof(float), stream);
  hipMemsetAsync(cnt, 0, (size_t)na * 4, stream);

  k_prep<<<64, 256, 0, stream>>>(wc1, wg1, wc2, wg2, wo, bc1, bg1,
                                 wpb, wpa, wpg, wc2t, wg2t, wot, biaspg);
  k_bw16<<<(na * KD / 8 + 255) / 256, 256, 0, stream>>>(bwt, bw16, na * KD / 8);

  const int tb = (na + 63) / 64;       // 625
  k_partial<256><<<tb, 256, 0, stream>>>(bond, wpb, (const float*)nullptr, PB, na);
  k_partial<128><<<tb, 256, 0, stream>>>(atom, wpa, (const float*)nullptr, PA, na);
  const int tg = (ng + 63) / 64;       // 7813
  k_partial<128><<<(tg < 2048 ? tg : 2048), 256, 0, stream>>>(ang, wpg, biaspg, PG, ng);

  k_hist<<<(ng + 255) / 256, 256, 0, stream>>>(bgr, cnt, ng);
  k_scan1<<<nblk, 256, 0, stream>>>(cnt, part, bsum, na);
  k_scan2<<<1, 1024, 0, stream>>>(bsum, bscan, nblk);
  k_scan3<<<nblk, 256, 0, stream>>>(part, bscan, offb, cur, na);
  k_fill<<<(ng + 255) / 256, 256, 0, stream>>>(bgr, offb, cur, ids4, ng);

  k_agg<<<tg, 256, 0, stream>>>(ids4, PB, PA, PG, wc2t, wg2t,
                                bc2, bg2, bw16, out, ng);

  k_out<<<(nb + 63) / 64, 256, 0, stream>>>(bond, wot, bo, out, nb);
}

// Round 7
// 331.099 us; speedup vs baseline: 5.0190x; 5.0190x over previous
//
#include <hip/hip_runtime.h>
#include <hip/hip_bf16.h>

static constexpr int KD  = 64;
static constexpr int KH  = 64;

typedef __attribute__((ext_vector_type(8))) short bf16x8;
typedef __attribute__((ext_vector_type(4))) float f32x4;
typedef __attribute__((ext_vector_type(2))) float f32x2;

__device__ inline unsigned short f2bf(float f) {
  union { float f; unsigned u; } uf; uf.f = f;
  unsigned u = uf.u;
  return (unsigned short)((u + 0x7FFFu + ((u >> 16) & 1u)) >> 16);
}
__device__ inline float bf2f(unsigned short h) {
  union { unsigned u; float f; } x; x.u = ((unsigned)h) << 16; return x.f;
}
__device__ inline bf16x8 pack8(const float* p) {
  float4 lo = *(const float4*)p;
  float4 hi = *(const float4*)(p + 4);
  bf16x8 v;
  v[0] = (short)f2bf(lo.x); v[1] = (short)f2bf(lo.y);
  v[2] = (short)f2bf(lo.z); v[3] = (short)f2bf(lo.w);
  v[4] = (short)f2bf(hi.x); v[5] = (short)f2bf(hi.y);
  v[6] = (short)f2bf(hi.z); v[7] = (short)f2bf(hi.w);
  return v;
}
__device__ inline float sigm(float x) { return 1.0f / (1.0f + __expf(-x)); }
__device__ inline float silu_(float x) { return x * sigm(x); }
__device__ inline unsigned pk_fp8x4(float a0, float a1, float a2, float a3) {
  int v = __builtin_amdgcn_cvt_pk_fp8_f32(a0, a1, 0, false);
  v = __builtin_amdgcn_cvt_pk_fp8_f32(a2, a3, v, true);
  return (unsigned)v;
}
__device__ inline void sum4_fp8(unsigned a, unsigned b, unsigned c, unsigned d, float* out) {
  f32x2 a0 = __builtin_amdgcn_cvt_pk_f32_fp8((int)a, false);
  f32x2 b0 = __builtin_amdgcn_cvt_pk_f32_fp8((int)b, false);
  f32x2 c0 = __builtin_amdgcn_cvt_pk_f32_fp8((int)c, false);
  f32x2 d0 = __builtin_amdgcn_cvt_pk_f32_fp8((int)d, false);
  out[0] = (a0[0] + b0[0]) + (c0[0] + d0[0]);
  out[1] = (a0[1] + b0[1]) + (c0[1] + d0[1]);
  f32x2 a1 = __builtin_amdgcn_cvt_pk_f32_fp8((int)a, true);
  f32x2 b1 = __builtin_amdgcn_cvt_pk_f32_fp8((int)b, true);
  f32x2 c1 = __builtin_amdgcn_cvt_pk_f32_fp8((int)c, true);
  f32x2 d1 = __builtin_amdgcn_cvt_pk_f32_fp8((int)d, true);
  out[2] = (a1[0] + b1[0]) + (c1[0] + d1[0]);
  out[3] = (a1[1] + b1[1]) + (c1[1] + d1[1]);
}

// ---------------- K0: frag-major W1 segment tables (bf16) + W2/Wo transposes ----
__global__ void k_prep(const float* __restrict__ wc1, const float* __restrict__ wg1,
                       const float* __restrict__ wc2, const float* __restrict__ wg2,
                       const float* __restrict__ wo,
                       const float* __restrict__ bc1, const float* __restrict__ bg1,
                       unsigned short* __restrict__ wpb, unsigned short* __restrict__ wpa,
                       unsigned short* __restrict__ wpg,
                       unsigned short* __restrict__ wc2t, unsigned short* __restrict__ wg2t,
                       unsigned short* __restrict__ wot, float* __restrict__ biaspg) {
  int t = blockIdx.x * 256 + threadIdx.x;
  if (t < 16384) {          // wpb: NOUT=256
    int blk = t >> 9, n = blk >> 1, s = blk & 1;
    int lane = (t >> 3) & 63, e = t & 7;
    int p = lane >> 4, q = lane & 15;
    int k = 32 * s + 8 * p + e;
    int o = 16 * n + q;
    float v;
    if (o < 64)       v = wc1[k * KH + o];                 // core1 (rows 0:64)
    else if (o < 128) v = wg1[k * KH + (o - 64)];          // gate1
    else if (o < 192) v = wc1[(64 + k) * KH + (o - 128)];  // core2 (rows 64:128)
    else              v = wg1[(64 + k) * KH + (o - 192)];  // gate2
    wpb[t] = f2bf(v);
  }
  if (t < 8192) {           // wpa / wpg: NOUT=128
    int blk = t >> 9, n = blk >> 1, s = blk & 1;
    int lane = (t >> 3) & 63, e = t & 7;
    int p = lane >> 4, q = lane & 15;
    int k = 32 * s + 8 * p + e;
    int o = 16 * n + q;
    float va = (o < 64) ? wc1[(192 + k) * KH + o] : wg1[(192 + k) * KH + (o - 64)];
    wpa[t] = f2bf(va);
    float vg = (o < 64) ? wc1[(128 + k) * KH + o] : wg1[(128 + k) * KH + (o - 64)];
    wpg[t] = f2bf(vg);
  }
  if (t < KH * KD) {        // natural B^T [d][k]
    int d = t >> 6, k = t & 63;
    wc2t[t] = f2bf(wc2[k * KD + d]);
    wg2t[t] = f2bf(wg2[k * KD + d]);
    wot[t]  = f2bf(wo[k * KD + d]);
  }
  if (t < 128) biaspg[t] = (t < 64) ? bc1[t] : bg1[t - 64];
}

// bond_weights (first na rows) -> bf16 table
__global__ void k_bw16(const float* __restrict__ bwt, unsigned short* __restrict__ bw16, int n8) {
  int t = blockIdx.x * 256 + threadIdx.x;
  if (t < n8) *(bf16x8*)(bw16 + (long)t * 8) = pack8(bwt + (long)t * 8);
}

// ---------------- passA: P[r][NOUT] = X[r][0:64] @ Wseg (+bias), fp8 out ------
template<int NOUT>
__global__ __launch_bounds__(256) void k_partial(
    const float* __restrict__ X, const unsigned short* __restrict__ wfrag,
    const float* __restrict__ bias, unsigned char* __restrict__ P, int nrows) {
  constexpr int NSH = NOUT * 64;
  __shared__ unsigned short wl[NSH];
  const int tid = threadIdx.x;
  for (int c = tid * 8; c < NSH; c += 256 * 8)
    *(bf16x8*)&wl[c] = *(const bf16x8*)&wfrag[c];
  __syncthreads();
  const int wave = tid >> 6, lane = tid & 63, p = lane >> 4, q = lane & 15;
  const int ntile = (nrows + 63) >> 6;
  for (int tile = blockIdx.x; tile < ntile; tile += gridDim.x) {
    const int r0 = tile * 64 + wave * 16 + q;
    const int r = (r0 < nrows) ? r0 : (nrows - 1);
    bf16x8 b[2];
    b[0] = pack8(X + (long)r * 64 + 8 * p);
    b[1] = pack8(X + (long)r * 64 + 32 + 8 * p);
    unsigned char* dst = P + (long)r0 * NOUT;
#pragma unroll
    for (int n = 0; n < NOUT / 16; n++) {
      f32x4 acc;
      if (bias) acc = (f32x4&)*(const float4*)(bias + 16 * n + 4 * p);
      else      acc = (f32x4){0.f, 0.f, 0.f, 0.f};
#pragma unroll
      for (int s = 0; s < 2; s++) {
        bf16x8 a = *(const bf16x8*)&wl[((n * 2 + s) * 64 + lane) * 8];
        acc = __builtin_amdgcn_mfma_f32_16x16x32_bf16(a, b[s], acc, 0, 0, 0);
      }
      if (r0 < nrows)
        *(unsigned*)(dst + 16 * n + 4 * p) = pk_fp8x4(acc[0], acc[1], acc[2], acc[3]);
    }
  }
}

// ---------------- CSR build (binned by bi, bins = na) ----------------
__global__ void k_hist(const int* __restrict__ bgr, int* __restrict__ cnt, int ng) {
  int g = blockIdx.x * blockDim.x + threadIdx.x;
  if (g < ng) atomicAdd(&cnt[bgr[3 * g + 1]], 1);
}

__global__ __launch_bounds__(256) void k_scan1(const int* __restrict__ cnt,
                                               int* __restrict__ part,
                                               int* __restrict__ bsum, int n) {
  __shared__ int wsum[4];
  const int tid = threadIdx.x;
  const int i = blockIdx.x * 256 + tid;
  const int lane = tid & 63, w = tid >> 6;
  int orig = (i < n) ? cnt[i] : 0;
  int v = orig;
#pragma unroll
  for (int d = 1; d < 64; d <<= 1) {
    int t = __shfl_up(v, d);
    if (lane >= d) v += t;
  }
  if (lane == 63) wsum[w] = v;
  __syncthreads();
  int add = 0;
  for (int k = 0; k < w; k++) add += wsum[k];
  v += add;
  if (i < n) part[i] = v - orig;
  if (tid == 255) bsum[blockIdx.x] = v;
}

__global__ __launch_bounds__(1024) void k_scan2(const int* __restrict__ bsum,
                                                int* __restrict__ bscan, int nblk) {
  __shared__ int wsum[16];
  const int tid = threadIdx.x;
  const int lane = tid & 63, w = tid >> 6;
  int orig = (tid < nblk) ? bsum[tid] : 0;
  int v = orig;
#pragma unroll
  for (int d = 1; d < 64; d <<= 1) {
    int t = __shfl_up(v, d);
    if (lane >= d) v += t;
  }
  if (lane == 63) wsum[w] = v;
  __syncthreads();
  int add = 0;
  for (int k = 0; k < w; k++) add += wsum[k];
  v += add;
  if (tid < nblk) bscan[tid] = v - orig;
}

__global__ void k_scan3(const int* __restrict__ part, const int* __restrict__ bscan,
                        int* __restrict__ off, int* __restrict__ cur, int n) {
  int i = blockIdx.x * blockDim.x + threadIdx.x;
  if (i < n) {
    off[i] = part[i] + bscan[i >> 8];
    cur[i] = 0;
  }
}

// fill packed records sorted by bi: {g, ci, bj, bi}
__global__ void k_fill(const int* __restrict__ bgr, const int* __restrict__ off,
                       int* __restrict__ cur, int4* __restrict__ ids4, int ng) {
  int g = blockIdx.x * blockDim.x + threadIdx.x;
  if (g < ng) {
    int ci = bgr[3 * g + 0];
    int bi = bgr[3 * g + 1];
    int bj = bgr[3 * g + 2];
    int slot = atomicAdd(&cur[bi], 1);
    int4 r; r.x = g; r.y = ci; r.z = bj; r.w = bi;
    ids4[off[bi] + slot] = r;
  }
}

// ---- k_agg: fp8 gather -> sum -> silu -> MFMA GEMM2 -> DENSE bf16 write (sorted order)
__global__ __launch_bounds__(256) void k_agg(
    const int4* __restrict__ ids4,
    const unsigned char* __restrict__ PB, const unsigned char* __restrict__ PA,
    const unsigned char* __restrict__ PG,
    const unsigned short* __restrict__ wc2t, const unsigned short* __restrict__ wg2t,
    const float* __restrict__ bc2, const float* __restrict__ bg2,
    const unsigned short* __restrict__ bw16,
    unsigned short* __restrict__ upd2, int ntot) {
  const int tid = threadIdx.x, wave = tid >> 6, lane = tid & 63;
  const int p = lane >> 4, q = lane & 15;
  const int pos = blockIdx.x * 64 + wave * 16 + q;
  const int4 r = ids4[(pos < ntot) ? pos : (ntot - 1)];
  const int g = r.x, ci = r.y, bj = r.z, bi = r.w;

  const unsigned char* rb1 = PB + (long)bi * 256;        // [c1 64|g1 64|c2 64|g2 64]
  const unsigned char* rb2 = PB + (long)bj * 256 + 128;
  const unsigned char* ra  = PA + (long)ci * 128;        // [c 64|g 64]
  const unsigned char* rg  = PG + (long)g  * 128;

  bf16x8 b2c[2], b2g[2];
#pragma unroll
  for (int s = 0; s < 2; s++) {
    const int o8 = 32 * s + 8 * p;
    uint2 v1 = *(const uint2*)(rb1 + o8);
    uint2 v2 = *(const uint2*)(rb2 + o8);
    uint2 v3 = *(const uint2*)(ra + o8);
    uint2 v4 = *(const uint2*)(rg + o8);
    uint2 w1 = *(const uint2*)(rb1 + 64 + o8);
    uint2 w2 = *(const uint2*)(rb2 + 64 + o8);
    uint2 w3 = *(const uint2*)(ra + 64 + o8);
    uint2 w4 = *(const uint2*)(rg + 64 + o8);
    float pc[8], pg_[8];
    sum4_fp8(v1.x, v2.x, v3.x, v4.x, pc + 0);
    sum4_fp8(v1.y, v2.y, v3.y, v4.y, pc + 4);
    sum4_fp8(w1.x, w2.x, w3.x, w4.x, pg_ + 0);
    sum4_fp8(w1.y, w2.y, w3.y, w4.y, pg_ + 4);
#pragma unroll
    for (int e = 0; e < 8; e++) {
      b2c[s][e] = (short)f2bf(silu_(pc[e]));
      b2g[s][e] = (short)f2bf(silu_(pg_[e]));
    }
  }

  // GEMM2 (transposed pattern): oc[n2][j] = O[d=16n2+4p+j][angle q]
  f32x4 oc[4], og[4];
#pragma unroll
  for (int n2 = 0; n2 < 4; n2++) {
    oc[n2] = (f32x4&)*(const float4*)(bc2 + 16 * n2 + 4 * p);
    og[n2] = (f32x4&)*(const float4*)(bg2 + 16 * n2 + 4 * p);
  }
#pragma unroll
  for (int s = 0; s < 2; s++) {
    const int ko = 32 * s + 8 * p;
#pragma unroll
    for (int n2 = 0; n2 < 4; n2++) {
      bf16x8 a1 = *(const bf16x8*)(wc2t + (q + 16 * n2) * KH + ko);
      oc[n2] = __builtin_amdgcn_mfma_f32_16x16x32_bf16(a1, b2c[s], oc[n2], 0, 0, 0);
      bf16x8 a2 = *(const bf16x8*)(wg2t + (q + 16 * n2) * KH + ko);
      og[n2] = __builtin_amdgcn_mfma_f32_16x16x32_bf16(a2, b2g[s], og[n2], 0, 0, 0);
    }
  }

  // dense write in sorted order: upd2[pos][d] = silu(oc)*sigm(og)*bw[bj][d]
  if (pos < ntot) {
    unsigned short* dst = upd2 + (long)pos * KD;
    const unsigned short* wj = bw16 + (long)bj * KD;
#pragma unroll
    for (int n2 = 0; n2 < 4; n2++) {
      const int d = 16 * n2 + 4 * p;
      ushort4 b = *(const ushort4*)(wj + d);
      ushort4 st;
      st.x = f2bf(silu_(oc[n2][0]) * sigm(og[n2][0]) * bf2f(b.x));
      st.y = f2bf(silu_(oc[n2][1]) * sigm(og[n2][1]) * bf2f(b.y));
      st.z = f2bf(silu_(oc[n2][2]) * sigm(og[n2][2]) * bf2f(b.z));
      st.w = f2bf(silu_(oc[n2][3]) * sigm(og[n2][3]) * bf2f(b.w));
      *(ushort4*)(dst + d) = st;
    }
  }
}

// ---- k_aggout: contiguous segment-sum(upd2) * bw[b] -> @Wo + bo + bond -> out
__global__ __launch_bounds__(256) void k_aggout(
    const float* __restrict__ bond, const float* __restrict__ bwt,
    const unsigned short* __restrict__ upd2,
    const int* __restrict__ off, const int* __restrict__ cnt,
    const unsigned short* __restrict__ wot, const float* __restrict__ bo,
    float* __restrict__ out, int na, int nb) {
  const int wave = threadIdx.x >> 6;
  const int lane = threadIdx.x & 63;
  const int r15 = lane & 15;
  const int ck = lane >> 4;
  const int base = blockIdx.x * 64 + wave * 16;
  const int b = base + r15;
  const bool bvalid = b < na;
  const int bc = bvalid ? b : 0;
  const int o = off[bc];
  const int c = bvalid ? cnt[bc] : 0;
  const int d0 = ck * 8;

  float acc[16];
#pragma unroll
  for (int e = 0; e < 16; e++) acc[e] = 0.0f;

  int it = 0;
  for (; it + 2 <= c; it += 2) {
    const unsigned short* r0 = upd2 + (long)(o + it) * KD;
    const unsigned short* r1 = r0 + KD;
    bf16x8 l0 = *(const bf16x8*)(r0 + d0);
    bf16x8 h0 = *(const bf16x8*)(r0 + 32 + d0);
    bf16x8 l1 = *(const bf16x8*)(r1 + d0);
    bf16x8 h1 = *(const bf16x8*)(r1 + 32 + d0);
#pragma unroll
    for (int e = 0; e < 8; e++) {
      acc[e]     += bf2f((unsigned short)l0[e]) + bf2f((unsigned short)l1[e]);
      acc[8 + e] += bf2f((unsigned short)h0[e]) + bf2f((unsigned short)h1[e]);
    }
  }
  if (it < c) {
    const unsigned short* r0 = upd2 + (long)(o + it) * KD;
    bf16x8 l0 = *(const bf16x8*)(r0 + d0);
    bf16x8 h0 = *(const bf16x8*)(r0 + 32 + d0);
#pragma unroll
    for (int e = 0; e < 8; e++) {
      acc[e]     += bf2f((unsigned short)l0[e]);
      acc[8 + e] += bf2f((unsigned short)h0[e]);
    }
  }

  {  // deferred bw[bi] factor
    const float* w = bwt + (long)bc * KD;
    float4 w0 = *(const float4*)(w + d0);
    float4 w1 = *(const float4*)(w + d0 + 4);
    float4 w2 = *(const float4*)(w + 32 + d0);
    float4 w3 = *(const float4*)(w + 32 + d0 + 4);
    acc[0] *= w0.x;  acc[1] *= w0.y;  acc[2] *= w0.z;  acc[3] *= w0.w;
    acc[4] *= w1.x;  acc[5] *= w1.y;  acc[6] *= w1.z;  acc[7] *= w1.w;
    acc[8] *= w2.x;  acc[9] *= w2.y;  acc[10] *= w2.z; acc[11] *= w2.w;
    acc[12] *= w3.x; acc[13] *= w3.y; acc[14] *= w3.z; acc[15] *= w3.w;
  }

  bf16x8 a[2];
#pragma unroll
  for (int e = 0; e < 8; e++) {
    a[0][e] = (short)f2bf(acc[e]);
    a[1][e] = (short)f2bf(acc[8 + e]);
  }

  f32x4 acc2[4];
#pragma unroll
  for (int n = 0; n < 4; n++) {
    float bv = bo[n * 16 + r15];
    acc2[n] = (f32x4){bv, bv, bv, bv};
  }
#pragma unroll
  for (int s = 0; s < 2; s++) {
    const int koff = s * 32 + ck * 8;
#pragma unroll
    for (int n = 0; n < 4; n++) {
      bf16x8 bf = *(const bf16x8*)(wot + (n * 16 + r15) * KH + koff);
      acc2[n] = __builtin_amdgcn_mfma_f32_16x16x32_bf16(a[s], bf, acc2[n], 0, 0, 0);
    }
  }
#pragma unroll
  for (int n = 0; n < 4; n++) {
#pragma unroll
    for (int j = 0; j < 4; j++) {
      const int orow = base + ck * 4 + j;
      if (orow < na) {
        const int d = n * 16 + r15;
        out[(long)orow * KD + d] = acc2[n][j] + bond[(long)orow * KD + d];
      }
    }
  }
}

// ---- k_tail: bonds [na, nb): empty segments -> out = bond + bo --------------
__global__ void k_tail(const float* __restrict__ bond, const float* __restrict__ bo,
                       float* __restrict__ out, int na, int nb) {
  const long nelem = (long)(nb - na) * KD;
  long i = ((long)blockIdx.x * blockDim.x + threadIdx.x) * 4;
  if (i < nelem) {
    const long ofs = (long)na * KD + i;
    float4 v = *(const float4*)(bond + ofs);
    const int d = (int)(i & 63);
    float4 bv = *(const float4*)(bo + d);
    v.x += bv.x; v.y += bv.y; v.z += bv.z; v.w += bv.w;
    *(float4*)(out + ofs) = v;
  }
}

extern "C" void kernel_launch(void* const* d_in, const int* in_sizes, int n_in,
                              void* d_out, int out_size, void* d_ws, size_t ws_size,
                              hipStream_t stream) {
  const float* atom = (const float*)d_in[0];
  const float* bond = (const float*)d_in[1];
  const float* bwt  = (const float*)d_in[2];
  const float* ang  = (const float*)d_in[3];
  const int*   bgr  = (const int*)d_in[4];
  const float* wc1 = (const float*)d_in[5];
  const float* bc1 = (const float*)d_in[6];
  const float* wc2 = (const float*)d_in[7];
  const float* bc2 = (const float*)d_in[8];
  const float* wg1 = (const float*)d_in[9];
  const float* bg1 = (const float*)d_in[10];
  const float* wg2 = (const float*)d_in[11];
  const float* bg2 = (const float*)d_in[12];
  const float* wo  = (const float*)d_in[13];
  const float* bo  = (const float*)d_in[14];

  const int na = in_sizes[0] / KD;   // atoms (40000); all bond_graph indices < na
  const int nb = in_sizes[1] / KD;   // bonds (200000)
  const int ng = in_sizes[4] / 3;    // angles (500000)
  float* out = (float*)d_out;

  char* pp = (char*)d_ws;
  auto alloc = [&](size_t bytes) { char* r = pp; pp += (bytes + 255) & ~(size_t)255; return r; };
  unsigned short* wpb  = (unsigned short*)alloc(16384 * 2);
  unsigned short* wpa  = (unsigned short*)alloc(8192 * 2);
  unsigned short* wpg  = (unsigned short*)alloc(8192 * 2);
  unsigned short* wc2t = (unsigned short*)alloc((size_t)KH * KD * 2);
  unsigned short* wg2t = (unsigned short*)alloc((size_t)KH * KD * 2);
  unsigned short* wot  = (unsigned short*)alloc((size_t)KH * KD * 2);
  float* biaspg        = (float*)alloc(128 * 4);
  unsigned short* bw16 = (unsigned short*)alloc((size_t)na * KD * 2);   // 5.1 MB
  unsigned char* PB    = (unsigned char*)alloc((size_t)na * 256);       // 10.2 MB
  unsigned char* PA    = (unsigned char*)alloc((size_t)na * 128);       // 5.1 MB
  unsigned char* PG    = (unsigned char*)alloc((size_t)ng * 128);       // 64 MB
  unsigned short* upd2 = (unsigned short*)alloc((size_t)ng * KD * 2);   // 64 MB
  int* cnt  = (int*)alloc((size_t)na * 4);
  int* cur  = (int*)alloc((size_t)na * 4);
  int* offb = (int*)alloc((size_t)na * 4);
  int* part = (int*)alloc((size_t)na * 4);
  int4* ids4 = (int4*)alloc((size_t)ng * 16);                           // 8 MB
  int* bsum  = (int*)alloc(4096);
  int* bscan = (int*)alloc(4096);

  const int nblk = (na + 255) / 256;   // 157 <= 1024

  hipMemsetAsync(cnt, 0, (size_t)na * 4, stream);

  k_prep<<<64, 256, 0, stream>>>(wc1, wg1, wc2, wg2, wo, bc1, bg1,
                                 wpb, wpa, wpg, wc2t, wg2t, wot, biaspg);
  k_bw16<<<(na * KD / 8 + 255) / 256, 256, 0, stream>>>(bwt, bw16, na * KD / 8);

  const int tb = (na + 63) / 64;       // 625
  k_partial<256><<<tb, 256, 0, stream>>>(bond, wpb, (const float*)nullptr, PB, na);
  k_partial<128><<<tb, 256, 0, stream>>>(atom, wpa, (const float*)nullptr, PA, na);
  const int tg = (ng + 63) / 64;       // 7813
  k_partial<128><<<(tg < 2048 ? tg : 2048), 256, 0, stream>>>(ang, wpg, biaspg, PG, ng);

  k_hist<<<(ng + 255) / 256, 256, 0, stream>>>(bgr, cnt, ng);
  k_scan1<<<nblk, 256, 0, stream>>>(cnt, part, bsum, na);
  k_scan2<<<1, 1024, 0, stream>>>(bsum, bscan, nblk);
  k_scan3<<<nblk, 256, 0, stream>>>(part, bscan, offb, cur, na);
  k_fill<<<(ng + 255) / 256, 256, 0, stream>>>(bgr, offb, cur, ids4, ng);

  k_agg<<<tg, 256, 0, stream>>>(ids4, PB, PA, PG, wc2t, wg2t,
                                bc2, bg2, bw16, upd2, ng);

  k_aggout<<<(na + 63) / 64, 256, 0, stream>>>(bond, bwt, upd2, offb, cnt,
                                               wot, bo, out, na, nb);

  const long tailelem = (long)(nb - na) * KD;
  k_tail<<<(int)((tailelem / 4 + 255) / 256), 256, 0, stream>>>(bond, bo, out, na, nb);
}